// Round 5
// baseline (464.776 us; speedup 1.0000x reference)
//
#include <hip/hip_runtime.h>
#include <hip/hip_bf16.h>
#include <stdint.h>

#define IN_F   16080
#define NTREES 64
#define NLEAF  128
#define NCLS   16
#define NBATCH 64
#define M_TOT  (NBATCH*NTREES)     // 4096
#define OUT_HALF (M_TOT*NLEAF)     // 524288

#define BM 64
#define BN 128
#define BK 64                          // 8 chunks of 8 bf16 per row
#define KSPLIT 16
#define NSTEPS ((IN_F + BK - 1)/BK)    // 252 (251 full + 16-elem tail)
#define NMBLK  (M_TOT / BM)            // 64

typedef __attribute__((ext_vector_type(8))) short short8;   // 8 x bf16
typedef __attribute__((ext_vector_type(4))) float f32x4;

typedef const __attribute__((address_space(1))) uint32_t gu32_t;
typedef __attribute__((address_space(3))) uint32_t su32_t;

// 8 fp32 -> short8 bf16 frag via packed RNE converts
__device__ __forceinline__ short8 cvt8(float4 lo, float4 hi){
  union { short8 s8; __hip_bfloat162 h2[4]; } u;
  u.h2[0] = __float22bfloat162_rn(make_float2(lo.x, lo.y));
  u.h2[1] = __float22bfloat162_rn(make_float2(lo.z, lo.w));
  u.h2[2] = __float22bfloat162_rn(make_float2(hi.x, hi.y));
  u.h2[3] = __float22bfloat162_rn(make_float2(hi.z, hi.w));
  return u.s8;
}

// One-shot W fp32 [128,16080] -> bf16 (RNE). Block 0 additionally zeroes the
// ticket array + zeropage (512 B); cross-kernel visibility to the gemm is
// guaranteed by the dispatch release/acquire protocol (same as the old
// hipMemsetAsync relied on). 8 elems/thread, 1005 blocks exactly.
__global__ __launch_bounds__(256)
void wcvt_kernel(const float* __restrict__ W, short* __restrict__ Wb,
                 uint32_t* __restrict__ zpt){
  if (blockIdx.x == 0 && threadIdx.x < 128) zpt[threadIdx.x] = 0u;
  int i = (blockIdx.x * 256 + threadIdx.x) << 3;
  float4 a = *(const float4*)(W + i);
  float4 b = *(const float4*)(W + i + 4);
  *(short8*)(Wb + i) = cvt8(a, b);
}

// ---------------- Fast path: bf16-B, slab split-K, fused epilogue ----------
// C = X[4096,16080] * W[128,16080]^T. Each kc writes its partial tile with
// plain stores to slabs[kc*OUT_HALF + ...]; the LAST kc block to finish each
// m-block (device-scope ticket) reduces the 16 slabs and applies
// bias/hardtanh + 16-class softmax Gini, writing both output halves.
//
// K-loop pipeline (unchanged from R4, verified): 2-deep B double-buffer,
// raw s_barrier + counted s_waitcnt vmcnt(4); A prefetched one step ahead.
__global__ __launch_bounds__(256, 4)
void gemm_slab_kernel(const float* __restrict__ X,
                      const short* __restrict__ Wb,
                      float* __restrict__ slabs,
                      const short* __restrict__ zeropage,
                      int* __restrict__ tickets,
                      float* __restrict__ out,
                      const float* __restrict__ bias,
                      const float* __restrict__ contrib){
  __shared__ __align__(16) short BsH[2][NLEAF * BK];   // 2 x 16 KB, chunk-swizzled
  __shared__ int s_last;

  const int tid = threadIdx.x;
  const int mb  = blockIdx.x;
  const int m0  = mb * BM;
  const int kc  = blockIdx.y;
  const int s0  = (kc * NSTEPS) / KSPLIT;
  const int s1  = ((kc + 1) * NSTEPS) / KSPLIT;

  const int lane = tid & 63;
  const int wv   = tid >> 6;
  const int wm   = wv & 1;        // 2 m-waves x 2 n-waves
  const int wn   = wv >> 1;
  const int fr   = lane & 15;     // row/col within 16x16 tile
  const int fq   = lane >> 4;     // k-quad

  f32x4 acc[2][4];
  #pragma unroll
  for (int mt = 0; mt < 2; ++mt)
    #pragma unroll
    for (int nt = 0; nt < 4; ++nt) acc[mt][nt] = (f32x4){0.f,0.f,0.f,0.f};

  float4 av[2][2][2];
  const float* arow[2];
  arow[0] = X + (size_t)(m0 + wm*32 + 0*16 + fr) * IN_F;
  arow[1] = X + (size_t)(m0 + wm*32 + 1*16 + fr) * IN_F;

  // --- prologue: stage step s0 ---
  {
    const int k0 = s0 * BK;
    #pragma unroll
    for (int j = 0; j < 4; ++j){
      int lin = j*256 + tid;              // lin = (row<<3)|p
      int r   = lin >> 3;
      int c   = (lin & 7) ^ (r & 7);
      int gk  = k0 + (c << 3);
      const short* gp = (gk + 8 <= IN_F) ? (Wb + (size_t)r * IN_F + gk)
                                         : zeropage;
      __builtin_amdgcn_global_load_lds((gu32_t*)gp, (su32_t*)(&BsH[0][0] + lin*8),
                                       16, 0, 0);
    }
    #pragma unroll
    for (int mt = 0; mt < 2; ++mt)
      #pragma unroll
      for (int h = 0; h < 2; ++h)
        #pragma unroll
        for (int q = 0; q < 2; ++q){
          int gk = k0 + h*32 + fq*8 + q*4;
          av[mt][h][q] = (gk + 4 <= IN_F) ? *(const float4*)(arow[mt] + gk)
                                          : make_float4(0.f,0.f,0.f,0.f);
        }
  }

  for (int s = s0; s < s1; ++s){
    const int par = (s - s0) & 1;
    short* bcur = &BsH[par][0];
    short* bnxt = &BsH[par ^ 1][0];

    // --- stage B for step s+1 (4 gload_lds; OOB -> zeropage) ---
    {
      const int k1 = (s + 1) * BK;
      #pragma unroll
      for (int j = 0; j < 4; ++j){
        int lin = j*256 + tid;
        int r   = lin >> 3;
        int c   = (lin & 7) ^ (r & 7);
        int gk  = k1 + (c << 3);
        const short* gp = (gk + 8 <= IN_F) ? (Wb + (size_t)r * IN_F + gk)
                                           : zeropage;
        __builtin_amdgcn_global_load_lds((gu32_t*)gp, (su32_t*)(bnxt + lin*8),
                                         16, 0, 0);
      }
    }

    // wait for step-s data (prev iter's 12 ops), keep this stage in flight
    asm volatile("s_waitcnt vmcnt(4)" ::: "memory");
    __builtin_amdgcn_s_barrier();

    // convert A for step s (frees av), then prefetch A for step s+1
    short8 af[2][2];
    #pragma unroll
    for (int mt = 0; mt < 2; ++mt)
      #pragma unroll
      for (int h = 0; h < 2; ++h)
        af[mt][h] = cvt8(av[mt][h][0], av[mt][h][1]);

    {
      const int k1 = (s + 1) * BK;
      #pragma unroll
      for (int mt = 0; mt < 2; ++mt)
        #pragma unroll
        for (int h = 0; h < 2; ++h)
          #pragma unroll
          for (int q = 0; q < 2; ++q){
            int gk = k1 + h*32 + fq*8 + q*4;
            av[mt][h][q] = (gk + 4 <= IN_F) ? *(const float4*)(arow[mt] + gk)
                                            : make_float4(0.f,0.f,0.f,0.f);
          }
    }

    // --- compute: 4 nt x 2 halves x 2 mt MFMAs; B frags read bf16-direct ---
    #pragma unroll
    for (int nt = 0; nt < 4; ++nt){
      const int l  = wn*64 + nt*16 + fr;
      const int xw = l & 7;
      const short* rowb = bcur + l*BK;     // 8 chunks of 8 bf16
      #pragma unroll
      for (int h = 0; h < 2; ++h){
        int cc = (((h << 2) + fq) ^ xw) << 3;          // element offset
        short8 bf = *(const short8*)(rowb + cc);       // MFMA-ready, no cvt
        #pragma unroll
        for (int mt = 0; mt < 2; ++mt)
          acc[mt][nt] = __builtin_amdgcn_mfma_f32_16x16x32_bf16(
                            af[mt][h], bf, acc[mt][nt], 0, 0, 0);
      }
    }

    __builtin_amdgcn_s_barrier();
  }

  // --- slab store. C/D layout: col = lane&15, row = (lane>>4)*4 + reg ---
  #pragma unroll
  for (int mt = 0; mt < 2; ++mt){
    const int rbase = m0 + wm*32 + mt*16 + fq*4;
    #pragma unroll
    for (int nt = 0; nt < 4; ++nt){
      int col = wn*64 + nt*16 + fr;
      #pragma unroll
      for (int r = 0; r < 4; ++r)
        slabs[(size_t)kc * OUT_HALF + (size_t)(rbase + r) * NLEAF + col]
            = acc[mt][nt][r];
    }
  }

  // --- ticket: last kc block for this m-block reduces + epilogue ---
  __syncthreads();   // all waves' slab stores drained (vmcnt0 before barrier)
  if (tid == 0){
    __builtin_amdgcn_fence(__ATOMIC_RELEASE, "agent");   // wb dirty L2 -> LLC
    int old = atomicAdd(&tickets[mb], 1);                // device-scope RMW
    s_last = (old == KSPLIT - 1) ? 1 : 0;
  }
  __syncthreads();
  if (!s_last) return;

  // acquire: invalidate possibly-stale (poison-era / cross-XCD) cached lines
  __builtin_amdgcn_fence(__ATOMIC_ACQUIRE, "agent");

  // 8192 outputs for this m-block, 32 per thread, lane-consecutive idx
  const size_t obase = (size_t)m0 * NLEAF;
  for (int j = 0; j < (BM * NLEAF) / 256; ++j){
    const int    il  = j * 256 + tid;        // 0..8191
    const size_t idx = obase + il;
    const int    l   = il & (NLEAF - 1);
    const int    t   = (il >> 7) & (NTREES - 1);   // m0 % 64 == 0

    float sum = 0.f;
    #pragma unroll
    for (int k = 0; k < KSPLIT; ++k)
      sum += slabs[(size_t)k * OUT_HALF + idx];
    float sv = fminf(1.f, fmaxf(-1.f, sum + bias[l]));
    out[idx] = sv;

    const float4* cp = (const float4*)(contrib + (((size_t)t * NLEAF + l) << 4));
    float4 c0 = cp[0], c1 = cp[1], c2 = cp[2], c3 = cp[3];
    float v[16] = { sv*c0.x, sv*c0.y, sv*c0.z, sv*c0.w,
                    sv*c1.x, sv*c1.y, sv*c1.z, sv*c1.w,
                    sv*c2.x, sv*c2.y, sv*c2.z, sv*c2.w,
                    sv*c3.x, sv*c3.y, sv*c3.z, sv*c3.w };
    float mx = v[0];
    #pragma unroll
    for (int c = 1; c < 16; ++c) mx = fmaxf(mx, v[c]);
    float se = 0.f, se2 = 0.f;
    #pragma unroll
    for (int c = 0; c < 16; ++c){
      float e = __expf(v[c] - mx);
      se  += e;
      se2 += e * e;
    }
    out[OUT_HALF + idx] = (float)NCLS - se2 / (se * se);
  }
}

// ---------------- Legacy path (harness-verified @429us) --------------------
// Used only when the workspace is too small for slabs+Wb. Needs 256 B of ws.
__global__ __launch_bounds__(256, 4)
void gemm_atomic_kernel(const float* __restrict__ X,
                        const float* __restrict__ Wg,
                        float* __restrict__ accbuf,
                        const float* __restrict__ zeropage){
  __shared__ __align__(16) float BsF[BN * BK];   // 32 KB, fp32, chunk-swizzled

  const int tid = threadIdx.x;
  const int m0  = blockIdx.x * BM;
  const int kc  = blockIdx.y;
  const int s0  = (kc * NSTEPS) / KSPLIT;
  const int s1  = ((kc + 1) * NSTEPS) / KSPLIT;

  const int lane = tid & 63;
  const int wv   = tid >> 6;
  const int wm   = wv & 1;
  const int wn   = wv >> 1;
  const int fr   = lane & 15;
  const int fq   = lane >> 4;

  f32x4 acc[2][4];
  #pragma unroll
  for (int mt = 0; mt < 2; ++mt)
    #pragma unroll
    for (int nt = 0; nt < 4; ++nt) acc[mt][nt] = (f32x4){0.f,0.f,0.f,0.f};

  for (int s = s0; s < s1; ++s){
    const int k0 = s * BK;
    __syncthreads();

    float4 av[2][2][2];
    #pragma unroll
    for (int mt = 0; mt < 2; ++mt){
      const float* rowp = X + (size_t)(m0 + wm*32 + mt*16 + fr) * IN_F;
      #pragma unroll
      for (int h = 0; h < 2; ++h)
        #pragma unroll
        for (int q = 0; q < 2; ++q){
          int gk = k0 + h*32 + fq*8 + q*4;
          av[mt][h][q] = (gk + 4 <= IN_F) ? *(const float4*)(rowp + gk)
                                          : make_float4(0.f,0.f,0.f,0.f);
        }
    }

    #pragma unroll
    for (int j = 0; j < 8; ++j){
      int lin = j*256 + tid;
      int r   = lin >> 4;
      int p   = lin & 15;
      int c   = p ^ (r & 7);
      int gk  = k0 + c*4;
      const float* gp = (gk + 4 <= IN_F) ? (Wg + (size_t)r * IN_F + gk)
                                         : zeropage;
      __builtin_amdgcn_global_load_lds((gu32_t*)gp, (su32_t*)(BsF + lin*4),
                                       16, 0, 0);
    }

    short8 af[2][2];
    #pragma unroll
    for (int mt = 0; mt < 2; ++mt)
      #pragma unroll
      for (int h = 0; h < 2; ++h)
        af[mt][h] = cvt8(av[mt][h][0], av[mt][h][1]);

    __syncthreads();

    #pragma unroll
    for (int nt = 0; nt < 4; ++nt){
      const int l  = wn*64 + nt*16 + fr;
      const int xw = l & 7;
      const float* rowb = BsF + l*64;
      #pragma unroll
      for (int h = 0; h < 2; ++h){
        int c0 = h*8 + fq*2;
        float4 b0 = *(const float4*)(rowb + ((c0    ) ^ xw)*4);
        float4 b1 = *(const float4*)(rowb + ((c0 + 1) ^ xw)*4);
        short8 bf = cvt8(b0, b1);
        #pragma unroll
        for (int mt = 0; mt < 2; ++mt)
          acc[mt][nt] = __builtin_amdgcn_mfma_f32_16x16x32_bf16(
                            af[mt][h], bf, acc[mt][nt], 0, 0, 0);
      }
    }
  }

  #pragma unroll
  for (int mt = 0; mt < 2; ++mt){
    const int rbase = m0 + wm*32 + mt*16 + fq*4;
    #pragma unroll
    for (int nt = 0; nt < 4; ++nt){
      int col = wn*64 + nt*16 + fr;
      #pragma unroll
      for (int r = 0; r < 4; ++r)
        atomicAdd(&accbuf[(size_t)(rbase + r) * NLEAF + col], acc[mt][nt][r]);
    }
  }
}

__global__ __launch_bounds__(256)
void epilogue_inplace_kernel(float* __restrict__ out,
                             const float* __restrict__ bias,
                             const float* __restrict__ contrib){
  int idx = blockIdx.x * 256 + threadIdx.x;   // < OUT_HALF
  int l   = idx & (NLEAF - 1);
  int row = idx >> 7;
  int t   = row & (NTREES - 1);

  float s = out[idx] + bias[l];
  s = fminf(1.f, fmaxf(-1.f, s));
  out[idx] = s;

  const float4* cp = (const float4*)(contrib + (((size_t)t * NLEAF + l) << 4));
  float4 c0 = cp[0], c1 = cp[1], c2 = cp[2], c3 = cp[3];
  float v[16] = { s*c0.x, s*c0.y, s*c0.z, s*c0.w,
                  s*c1.x, s*c1.y, s*c1.z, s*c1.w,
                  s*c2.x, s*c2.y, s*c2.z, s*c2.w,
                  s*c3.x, s*c3.y, s*c3.z, s*c3.w };
  float m = v[0];
  #pragma unroll
  for (int c = 1; c < 16; ++c) m = fmaxf(m, v[c]);
  float se = 0.f, se2 = 0.f;
  #pragma unroll
  for (int c = 0; c < 16; ++c){
    float e = __expf(v[c] - m);
    se  += e;
    se2 += e * e;
  }
  out[OUT_HALF + idx] = (float)NCLS - se2 / (se * se);
}

extern "C" void kernel_launch(void* const* d_in, const int* in_sizes, int n_in,
                              void* d_out, int out_size, void* d_ws, size_t ws_size,
                              hipStream_t stream){
  const float* X       = (const float*)d_in[0];   // [64,64,16080]
  const float* Wg      = (const float*)d_in[1];   // [128,16080]
  const float* bias    = (const float*)d_in[2];   // [128]
  const float* contrib = (const float*)d_in[3];   // [64,128,16]
  float* out = (float*)d_out;

  const size_t SLAB_BYTES = (size_t)KSPLIT * OUT_HALF * sizeof(float); // 33.55 MB
  const size_t WB_BYTES   = (size_t)NLEAF * IN_F * sizeof(short);      // 4.12 MB
  char* ws = (char*)d_ws;
  const int WCVT_BLOCKS = (NLEAF * IN_F) / (256 * 8);                  // 1005

  dim3 g1(NMBLK, KSPLIT);

  if (ws_size >= SLAB_BYTES + WB_BYTES + 512){
    // ws layout: [16 slabs 33.55MB][W_bf16 4.12MB][tickets 256B][zero page 256B]
    float* slabs   = (float*)ws;
    short* Wb      = (short*)(ws + SLAB_BYTES);
    int*   tickets = (int*)(ws + SLAB_BYTES + WB_BYTES);
    short* zp      = (short*)(ws + SLAB_BYTES + WB_BYTES + 256);
    // wcvt also zeroes tickets+zp (512 B); dispatch-boundary release/acquire
    // makes them visible to the gemm.
    wcvt_kernel<<<WCVT_BLOCKS, 256, 0, stream>>>(Wg, Wb,
                   (uint32_t*)(ws + SLAB_BYTES + WB_BYTES));
    gemm_slab_kernel<<<g1, 256, 0, stream>>>(X, Wb, slabs, zp, tickets,
                                             out, bias, contrib);
  } else {
    // legacy harness-verified path: fp32 W staged per-step, atomic split-K.
    hipMemsetAsync(out, 0, (size_t)OUT_HALF * sizeof(float), stream);
    hipMemsetAsync(ws, 0, 256, stream);
    gemm_atomic_kernel<<<g1, 256, 0, stream>>>(X, Wg, out, (const float*)ws);
    epilogue_inplace_kernel<<<OUT_HALF / 256, 256, 0, stream>>>(out, bias, contrib);
  }
}

// Round 7
// 393.513 us; speedup vs baseline: 1.1811x; 1.1811x over previous
//
#include <hip/hip_runtime.h>
#include <hip/hip_bf16.h>
#include <stdint.h>

#define IN_F   16080
#define NTREES 64
#define NLEAF  128
#define NCLS   16
#define NBATCH 64
#define M_TOT  (NBATCH*NTREES)     // 4096
#define OUT_HALF (M_TOT*NLEAF)     // 524288

#define BM 64
#define BN 128
#define BK 64                          // 8 chunks of 8 bf16 per row
#define KSPLIT 16
#define NSTEPS ((IN_F + BK - 1)/BK)    // 252 (251 full + 16-elem tail)
#define NMBLK  (M_TOT / BM)            // 64

typedef __attribute__((ext_vector_type(8))) short short8;   // 8 x bf16
typedef __attribute__((ext_vector_type(4))) float f32x4;

typedef const __attribute__((address_space(1))) uint32_t gu32_t;
typedef __attribute__((address_space(3))) uint32_t su32_t;

// 8 fp32 -> short8 bf16 frag via packed RNE converts
__device__ __forceinline__ short8 cvt8(float4 lo, float4 hi){
  union { short8 s8; __hip_bfloat162 h2[4]; } u;
  u.h2[0] = __float22bfloat162_rn(make_float2(lo.x, lo.y));
  u.h2[1] = __float22bfloat162_rn(make_float2(lo.z, lo.w));
  u.h2[2] = __float22bfloat162_rn(make_float2(hi.x, hi.y));
  u.h2[3] = __float22bfloat162_rn(make_float2(hi.z, hi.w));
  return u.s8;
}

// One-shot W fp32 [128,16080] -> bf16 (RNE). Block 0 additionally zeroes the
// 256 B zeropage (cross-dispatch visibility via the kernel-boundary
// release/acquire protocol — verified passing in R5). 1005 blocks exactly.
__global__ __launch_bounds__(256)
void wcvt_kernel(const float* __restrict__ W, short* __restrict__ Wb,
                 uint32_t* __restrict__ zp){
  if (blockIdx.x == 0 && threadIdx.x < 64) zp[threadIdx.x] = 0u;
  int i = (blockIdx.x * 256 + threadIdx.x) << 3;
  float4 a = *(const float4*)(W + i);
  float4 b = *(const float4*)(W + i + 4);
  *(short8*)(Wb + i) = cvt8(a, b);
}

// ---------------- Fast path: bf16-B, slab split-K, 2-deep pipeline ---------
// C = X[4096,16080] * W[128,16080]^T. Each kc writes its partial tile with
// plain stores to slabs[kc*OUT_HALF + ...]; epilogue reduces the 16 slabs.
//
// Wave decomposition (R6): 4 m-strips x full-N. Wave wv owns rows
// m0+wv*16+fr and ALL 128 cols (nt=0..7). Every wave's A rows are UNIQUE,
// so the A tile is fetched exactly once per block per step (R5 counters
// showed the old 2m x 2n split fetched A twice: 48 MB/step issued, GEMM
// stuck at 3.2% MfmaUtil / 13.6% HBM — memory-service-bound).
//
// K-loop pipeline (R4-verified): 2-deep B double-buffer, raw s_barrier +
// counted s_waitcnt vmcnt(4); A prefetched one step ahead.
//   iter s: STAGE_B(buf[nxt], s+1)      // 4 vm ops
//           s_waitcnt vmcnt(4)          // newest 4 = this stage; retires
//                                       // prev iter's 4 A-loads + 4 B-stage
//           s_barrier                   // buf[cur] resident for all waves
//           af = cvt8(av); LOAD_A(av, s+1)   // A prefetch overlaps MFMA
//           ds_read buf[cur] -> 16 MFMA
//           s_barrier                   // readers done; bcur reusable at s+2
__global__ __launch_bounds__(256, 4)
void gemm_slab_kernel(const float* __restrict__ X,
                      const short* __restrict__ Wb,
                      float* __restrict__ slabs,
                      const short* __restrict__ zeropage){
  __shared__ __align__(16) short BsH[2][NLEAF * BK];   // 2 x 16 KB, chunk-swizzled

  const int tid = threadIdx.x;
  const int m0  = blockIdx.x * BM;
  const int kc  = blockIdx.y;
  const int s0  = (kc * NSTEPS) / KSPLIT;
  const int s1  = ((kc + 1) * NSTEPS) / KSPLIT;

  const int lane = tid & 63;
  const int wv   = tid >> 6;      // m-strip index, 0..3
  const int fr   = lane & 15;     // row/col within 16x16 tile
  const int fq   = lane >> 4;     // k-quad

  f32x4 acc[8];
  #pragma unroll
  for (int nt = 0; nt < 8; ++nt) acc[nt] = (f32x4){0.f,0.f,0.f,0.f};

  float4 av[2][2];                // [h][q] — one 16-row strip, K=64
  const float* arow = X + (size_t)(m0 + wv*16 + fr) * IN_F;

  // --- prologue: stage step s0 ---
  {
    const int k0 = s0 * BK;
    #pragma unroll
    for (int j = 0; j < 4; ++j){
      int lin = j*256 + tid;              // lin = (row<<3)|p
      int r   = lin >> 3;
      int c   = (lin & 7) ^ (r & 7);
      int gk  = k0 + (c << 3);
      const short* gp = (gk + 8 <= IN_F) ? (Wb + (size_t)r * IN_F + gk)
                                         : zeropage;
      __builtin_amdgcn_global_load_lds((gu32_t*)gp, (su32_t*)(&BsH[0][0] + lin*8),
                                       16, 0, 0);
    }
    #pragma unroll
    for (int h = 0; h < 2; ++h)
      #pragma unroll
      for (int q = 0; q < 2; ++q){
        int gk = k0 + h*32 + fq*8 + q*4;
        av[h][q] = (gk + 4 <= IN_F) ? *(const float4*)(arow + gk)
                                    : make_float4(0.f,0.f,0.f,0.f);
      }
  }

  for (int s = s0; s < s1; ++s){
    const int par = (s - s0) & 1;
    short* bcur = &BsH[par][0];
    short* bnxt = &BsH[par ^ 1][0];

    // --- stage B for step s+1 (4 gload_lds; OOB -> zeropage) ---
    {
      const int k1 = (s + 1) * BK;
      #pragma unroll
      for (int j = 0; j < 4; ++j){
        int lin = j*256 + tid;
        int r   = lin >> 3;
        int c   = (lin & 7) ^ (r & 7);
        int gk  = k1 + (c << 3);
        const short* gp = (gk + 8 <= IN_F) ? (Wb + (size_t)r * IN_F + gk)
                                           : zeropage;
        __builtin_amdgcn_global_load_lds((gu32_t*)gp, (su32_t*)(bnxt + lin*8),
                                         16, 0, 0);
      }
    }

    // wait for step-s data (prev iter's 8 ops), keep this stage in flight
    asm volatile("s_waitcnt vmcnt(4)" ::: "memory");
    __builtin_amdgcn_s_barrier();

    // convert A for step s (frees av), then prefetch A for step s+1
    short8 af[2];
    #pragma unroll
    for (int h = 0; h < 2; ++h)
      af[h] = cvt8(av[h][0], av[h][1]);

    {
      const int k1 = (s + 1) * BK;
      #pragma unroll
      for (int h = 0; h < 2; ++h)
        #pragma unroll
        for (int q = 0; q < 2; ++q){
          int gk = k1 + h*32 + fq*8 + q*4;
          av[h][q] = (gk + 4 <= IN_F) ? *(const float4*)(arow + gk)
                                      : make_float4(0.f,0.f,0.f,0.f);
        }
    }

    // --- compute: 8 nt x 2 halves MFMAs; B frags read bf16-direct ---
    #pragma unroll
    for (int nt = 0; nt < 8; ++nt){
      const int l  = nt*16 + fr;
      const int xw = l & 7;
      const short* rowb = bcur + l*BK;     // 8 chunks of 8 bf16
      #pragma unroll
      for (int h = 0; h < 2; ++h){
        int cc = (((h << 2) + fq) ^ xw) << 3;          // element offset
        short8 bf = *(const short8*)(rowb + cc);       // MFMA-ready, no cvt
        acc[nt] = __builtin_amdgcn_mfma_f32_16x16x32_bf16(
                      af[h], bf, acc[nt], 0, 0, 0);
      }
    }

    __builtin_amdgcn_s_barrier();
  }

  // --- slab store. C/D layout: col = lane&15, row = (lane>>4)*4 + reg ---
  const int rbase = m0 + wv*16 + fq*4;
  #pragma unroll
  for (int nt = 0; nt < 8; ++nt){
    int col = nt*16 + fr;
    #pragma unroll
    for (int r = 0; r < 4; ++r)
      slabs[(size_t)kc * OUT_HALF + (size_t)(rbase + r) * NLEAF + col]
          = acc[nt][r];
  }
}

// Epilogue for the slab path: reduce 16 partial slabs, then bias/hardtanh
// + 16-class softmax Gini.
__global__ __launch_bounds__(256)
void epilogue_slab_kernel(const float* __restrict__ slabs,
                          float* __restrict__ out,
                          const float* __restrict__ bias,
                          const float* __restrict__ contrib){
  int idx = blockIdx.x * 256 + threadIdx.x;   // < OUT_HALF
  int l   = idx & (NLEAF - 1);
  int row = idx >> 7;
  int t   = row & (NTREES - 1);

  float s = 0.f;
  #pragma unroll
  for (int kc = 0; kc < KSPLIT; ++kc)
    s += slabs[(size_t)kc * OUT_HALF + idx];
  s += bias[l];
  s = fminf(1.f, fmaxf(-1.f, s));
  out[idx] = s;

  const float4* cp = (const float4*)(contrib + (((size_t)t * NLEAF + l) << 4));
  float4 c0 = cp[0], c1 = cp[1], c2 = cp[2], c3 = cp[3];
  float v[16] = { s*c0.x, s*c0.y, s*c0.z, s*c0.w,
                  s*c1.x, s*c1.y, s*c1.z, s*c1.w,
                  s*c2.x, s*c2.y, s*c2.z, s*c2.w,
                  s*c3.x, s*c3.y, s*c3.z, s*c3.w };
  float m = v[0];
  #pragma unroll
  for (int c = 1; c < 16; ++c) m = fmaxf(m, v[c]);
  float se = 0.f, se2 = 0.f;
  #pragma unroll
  for (int c = 0; c < 16; ++c){
    float e = __expf(v[c] - m);
    se  += e;
    se2 += e * e;
  }
  out[OUT_HALF + idx] = (float)NCLS - se2 / (se * se);
}

// ---------------- Legacy path (harness-verified @429us) --------------------
// Used only when the workspace is too small for slabs+Wb. Needs 256 B of ws.
__global__ __launch_bounds__(256, 4)
void gemm_atomic_kernel(const float* __restrict__ X,
                        const float* __restrict__ Wg,
                        float* __restrict__ accbuf,
                        const float* __restrict__ zeropage){
  __shared__ __align__(16) float BsF[BN * BK];   // 32 KB, fp32, chunk-swizzled

  const int tid = threadIdx.x;
  const int m0  = blockIdx.x * BM;
  const int kc  = blockIdx.y;
  const int s0  = (kc * NSTEPS) / KSPLIT;
  const int s1  = ((kc + 1) * NSTEPS) / KSPLIT;

  const int lane = tid & 63;
  const int wv   = tid >> 6;
  const int wm   = wv & 1;
  const int wn   = wv >> 1;
  const int fr   = lane & 15;
  const int fq   = lane >> 4;

  f32x4 acc[2][4];
  #pragma unroll
  for (int mt = 0; mt < 2; ++mt)
    #pragma unroll
    for (int nt = 0; nt < 4; ++nt) acc[mt][nt] = (f32x4){0.f,0.f,0.f,0.f};

  for (int s = s0; s < s1; ++s){
    const int k0 = s * BK;
    __syncthreads();

    float4 av[2][2][2];
    #pragma unroll
    for (int mt = 0; mt < 2; ++mt){
      const float* rowp = X + (size_t)(m0 + wm*32 + mt*16 + fr) * IN_F;
      #pragma unroll
      for (int h = 0; h < 2; ++h)
        #pragma unroll
        for (int q = 0; q < 2; ++q){
          int gk = k0 + h*32 + fq*8 + q*4;
          av[mt][h][q] = (gk + 4 <= IN_F) ? *(const float4*)(rowp + gk)
                                          : make_float4(0.f,0.f,0.f,0.f);
        }
    }

    #pragma unroll
    for (int j = 0; j < 8; ++j){
      int lin = j*256 + tid;
      int r   = lin >> 4;
      int p   = lin & 15;
      int c   = p ^ (r & 7);
      int gk  = k0 + c*4;
      const float* gp = (gk + 4 <= IN_F) ? (Wg + (size_t)r * IN_F + gk)
                                         : zeropage;
      __builtin_amdgcn_global_load_lds((gu32_t*)gp, (su32_t*)(BsF + lin*4),
                                       16, 0, 0);
    }

    short8 af[2][2];
    #pragma unroll
    for (int mt = 0; mt < 2; ++mt)
      #pragma unroll
      for (int h = 0; h < 2; ++h)
        af[mt][h] = cvt8(av[mt][h][0], av[mt][h][1]);

    __syncthreads();

    #pragma unroll
    for (int nt = 0; nt < 4; ++nt){
      const int l  = wn*64 + nt*16 + fr;
      const int xw = l & 7;
      const float* rowb = BsF + l*64;
      #pragma unroll
      for (int h = 0; h < 2; ++h){
        int c0 = h*8 + fq*2;
        float4 b0 = *(const float4*)(rowb + ((c0    ) ^ xw)*4);
        float4 b1 = *(const float4*)(rowb + ((c0 + 1) ^ xw)*4);
        short8 bf = cvt8(b0, b1);
        #pragma unroll
        for (int mt = 0; mt < 2; ++mt)
          acc[mt][nt] = __builtin_amdgcn_mfma_f32_16x16x32_bf16(
                            af[mt][h], bf, acc[mt][nt], 0, 0, 0);
      }
    }
  }

  #pragma unroll
  for (int mt = 0; mt < 2; ++mt){
    const int rbase = m0 + wm*32 + mt*16 + fq*4;
    #pragma unroll
    for (int nt = 0; nt < 4; ++nt){
      int col = wn*64 + nt*16 + fr;
      #pragma unroll
      for (int r = 0; r < 4; ++r)
        atomicAdd(&accbuf[(size_t)(rbase + r) * NLEAF + col], acc[mt][nt][r]);
    }
  }
}

__global__ __launch_bounds__(256)
void epilogue_inplace_kernel(float* __restrict__ out,
                             const float* __restrict__ bias,
                             const float* __restrict__ contrib){
  int idx = blockIdx.x * 256 + threadIdx.x;   // < OUT_HALF
  int l   = idx & (NLEAF - 1);
  int row = idx >> 7;
  int t   = row & (NTREES - 1);

  float s = out[idx] + bias[l];
  s = fminf(1.f, fmaxf(-1.f, s));
  out[idx] = s;

  const float4* cp = (const float4*)(contrib + (((size_t)t * NLEAF + l) << 4));
  float4 c0 = cp[0], c1 = cp[1], c2 = cp[2], c3 = cp[3];
  float v[16] = { s*c0.x, s*c0.y, s*c0.z, s*c0.w,
                  s*c1.x, s*c1.y, s*c1.z, s*c1.w,
                  s*c2.x, s*c2.y, s*c2.z, s*c2.w,
                  s*c3.x, s*c3.y, s*c3.z, s*c3.w };
  float m = v[0];
  #pragma unroll
  for (int c = 1; c < 16; ++c) m = fmaxf(m, v[c]);
  float se = 0.f, se2 = 0.f;
  #pragma unroll
  for (int c = 0; c < 16; ++c){
    float e = __expf(v[c] - m);
    se  += e;
    se2 += e * e;
  }
  out[OUT_HALF + idx] = (float)NCLS - se2 / (se * se);
}

extern "C" void kernel_launch(void* const* d_in, const int* in_sizes, int n_in,
                              void* d_out, int out_size, void* d_ws, size_t ws_size,
                              hipStream_t stream){
  const float* X       = (const float*)d_in[0];   // [64,64,16080]
  const float* Wg      = (const float*)d_in[1];   // [128,16080]
  const float* bias    = (const float*)d_in[2];   // [128]
  const float* contrib = (const float*)d_in[3];   // [64,128,16]
  float* out = (float*)d_out;

  const size_t SLAB_BYTES = (size_t)KSPLIT * OUT_HALF * sizeof(float); // 33.55 MB
  const size_t WB_BYTES   = (size_t)NLEAF * IN_F * sizeof(short);      // 4.12 MB
  char* ws = (char*)d_ws;
  const int WCVT_BLOCKS = (NLEAF * IN_F) / (256 * 8);                  // 1005

  dim3 g1(NMBLK, KSPLIT);

  if (ws_size >= SLAB_BYTES + WB_BYTES + 256){
    // ws layout: [16 slabs 33.55MB][W_bf16 4.12MB][zero page 256B]
    float* slabs = (float*)ws;
    short* Wb    = (short*)(ws + SLAB_BYTES);
    short* zp    = (short*)(ws + SLAB_BYTES + WB_BYTES);
    // wcvt zeroes zp (256 B); dispatch-boundary release/acquire makes it
    // visible to the gemm (verified passing in R5).
    wcvt_kernel<<<WCVT_BLOCKS, 256, 0, stream>>>(Wg, Wb, (uint32_t*)zp);
    gemm_slab_kernel<<<g1, 256, 0, stream>>>(X, Wb, slabs, zp);
    epilogue_slab_kernel<<<OUT_HALF / 256, 256, 0, stream>>>(slabs, out, bias, contrib);
  } else {
    // legacy harness-verified path: fp32 W staged per-step, atomic split-K.
    hipMemsetAsync(out, 0, (size_t)OUT_HALF * sizeof(float), stream);
    hipMemsetAsync(ws, 0, 256, stream);
    gemm_atomic_kernel<<<g1, 256, 0, stream>>>(X, Wg, out, (const float*)ws);
    epilogue_inplace_kernel<<<OUT_HALF / 256, 256, 0, stream>>>(out, bias, contrib);
  }
}